// Round 1
// 647.054 us; speedup vs baseline: 1.0265x; 1.0265x over previous
//
#include <hip/hip_runtime.h>
#include <math.h>

// B=8, N=40962, D=40, H=512, D_DYN=32, 4 steps, dt=0.1
constexpr int BB   = 8;
constexpr int NN   = 40962;
constexpr int DDIM = 40;
constexpr int HH   = 512;
constexpr int DDYN = 32;
constexpr float STEPSZ = 0.1f;

constexpr int TM   = 64;      // nodes per block (was 32): halves W1p L2 traffic per node
constexpr int NTHR = 1024;    // 16 waves
constexpr int ZS   = 168;     // z row stride (bf16): 336B -> 2-way banks (free)

constexpr size_t X_ELEMS = (size_t)BB * NN * DDIM;
constexpr size_t X_BYTES = X_ELEMS * 4;
constexpr int W1P_ELEMS = 32 * 5 * 64 * 8;   // bf16 A-frags [mt][kk][lane][j]
constexpr int W2P_BYTES = 2 * 16 * 64 * 8;   // fp8 A-frags  [jt][kk][lane][j]

// LDS: z [64][168] bf16 = 21504 | h [64][512] fp8 = 32768 | xself [64][40] f32 = 10240
// fz (2x 64x36 f32 = 18432) overlays z. Total 64512 (<64KiB), 2 blocks/CU.
constexpr int Z_BYTES = TM * ZS * 2;             // 21504
constexpr int H_OFF   = Z_BYTES;                 // 21504 (16-aligned)
constexpr int H_BYTES = TM * HH;                 // 32768
constexpr int XS_OFF  = H_OFF + H_BYTES;         // 54272 (16-aligned)
constexpr int LDS_TOT = XS_OFF + TM * DDIM * 4;  // 64512

typedef __attribute__((ext_vector_type(8))) short short8;
typedef __attribute__((ext_vector_type(4))) float f32x4;
typedef __attribute__((ext_vector_type(4))) unsigned short u16x4;

__device__ __forceinline__ unsigned short bf16_rne(float f) {
    unsigned int u = __float_as_uint(f);
    return (unsigned short)((u + 0x7FFFu + ((u >> 16) & 1u)) >> 16);
}

// HW packed f32->bf16 (2 elems / inst), gfx950
__device__ __forceinline__ unsigned int cvt_pk_bf16(float lo, float hi) {
    unsigned int r;
    asm("v_cvt_pk_bf16_f32 %0, %1, %2" : "=v"(r) : "v"(lo), "v"(hi));
    return r;
}

__device__ __forceinline__ float exp2_hw(float x) {
    float r;
    asm("v_exp_f32 %0, %1" : "=v"(r) : "v"(x));
    return r;
}

__device__ __forceinline__ unsigned char f32_to_fp8_sw(float f) {
    if (!(f == f)) return 0x7f;
    unsigned u = __float_as_uint(f);
    unsigned s = (u >> 24) & 0x80u;
    float a = fabsf(f);
    if (a >= 464.f) return (unsigned char)(s | 0x7e);
    int e = (int)((u >> 23) & 0xff) - 127;
    if (e < -6) {
        int q = (int)fminf(fmaxf(a * 512.0f + 0.5f, 0.f), 7.f);
        return (unsigned char)(s | q);
    }
    unsigned m = u & 0x7fffffu;
    unsigned keep = m >> 20, rest = m & 0xfffffu;
    keep += (rest > 0x80000u || (rest == 0x80000u && (keep & 1u))) ? 1u : 0u;
    if (keep == 8u) { keep = 0u; ++e; if (e > 8) return (unsigned char)(s | 0x7e); }
    return (unsigned char)(s | ((unsigned)(e + 7) << 3) | keep);
}

__device__ __forceinline__ unsigned int pk4_fp8(float a, float b, float c, float d) {
#if __has_builtin(__builtin_amdgcn_cvt_pk_fp8_f32)
    int r = __builtin_amdgcn_cvt_pk_fp8_f32(a, b, 0, false);
    r     = __builtin_amdgcn_cvt_pk_fp8_f32(c, d, r, true);
    return (unsigned int)r;
#else
    return (unsigned)f32_to_fp8_sw(a) | ((unsigned)f32_to_fp8_sw(b) << 8) |
           ((unsigned)f32_to_fp8_sw(c) << 16) | ((unsigned)f32_to_fp8_sw(d) << 24);
#endif
}

// gelu tanh-approx: x * sigmoid(1.59577*(x + 0.044715 x^3));
// exp folded to exp2: 1.5957691216 * log2(e) = 2.30220817
__device__ __forceinline__ float gelu_fast(float x) {
    float u = x * fmaf(0.044715f, x * x, 1.0f);
    float e = exp2_hw(-2.30220817f * u);
    return x * __builtin_amdgcn_rcpf(1.0f + e);
}

// W1p bf16 A-frags: t = ((mt*5+kk)*64 + lane)*8 + j ; A[m=mt*16+nl][k=kk*32+q*8+j] = W1[k][m]
__global__ __launch_bounds__(256) void pack_w1(const float* __restrict__ W1,
                                               unsigned short* __restrict__ W1p) {
    int t = blockIdx.x * 256 + threadIdx.x;
    if (t >= W1P_ELEMS) return;
    int j = t & 7, ln = (t >> 3) & 63, g = t >> 9;
    int kk = g % 5, mt = g / 5;
    int nl = ln & 15, q = ln >> 4;
    int k = kk * 32 + q * 8 + j, m = mt * 16 + nl;
    W1p[t] = bf16_rne(W1[(size_t)k * HH + m]);
}
// W2p fp8 A-frags: t = ((jt*16+kk)*64 + lane)*8 + j ; A[m=jt*16+nl][k=kk*32+q*8+j] = W2[k][m]
__global__ __launch_bounds__(256) void pack_w2_fp8(const float* __restrict__ W2,
                                                   unsigned char* __restrict__ W2p) {
    int t = blockIdx.x * 256 + threadIdx.x;
    if (t >= W2P_BYTES) return;
    int j = t & 7, ln = (t >> 3) & 63, g = t >> 9;
    int kk = g & 15, jt = g >> 4;
    int nl = ln & 15, q = ln >> 4;
    int k = kk * 32 + q * 8 + j, m = jt * 16 + nl;
    float v = W2[(size_t)k * DDYN + m];
#if __has_builtin(__builtin_amdgcn_cvt_pk_fp8_f32)
    W2p[t] = (unsigned char)(__builtin_amdgcn_cvt_pk_fp8_f32(v, v, 0, false) & 0xff);
#else
    W2p[t] = f32_to_fp8_sw(v);
#endif
}

// h: [node(64)][hid(512)] fp8, XOR-swizzled 8B subs: byte = node*512 + ((sub8 ^ (node&7))<<3) + (hid&7)
__global__ __launch_bounds__(NTHR, 8) void step_mfma(
    const float* __restrict__ xsrc, float* __restrict__ xdst,
    const int* __restrict__ index,
    const unsigned short* __restrict__ W1p, const float* __restrict__ b1,
    const unsigned char* __restrict__ W2p, const float* __restrict__ b2)
{
    __shared__ alignas(16) unsigned char smem[LDS_TOT];
    unsigned short* z = (unsigned short*)smem;          // [64][ZS] bf16, dies after GEMM1
    unsigned char*  h = smem + H_OFF;                   // [64][512] fp8 swizzled
    float* xself = (float*)(smem + XS_OFF);             // [64][40] f32 self rows
    float* fz0 = (float*)smem;                          // [64][36] f32 (overlay z)
    float* fz1 = (float*)(smem + TM * 36 * 4);          // [64][36] f32

    const int tid = threadIdx.x;
    const int w   = tid >> 6;        // 0..15
    const int ln  = tid & 63;
    const int nl  = ln & 15;
    const int q   = ln >> 4;
    const int n0  = blockIdx.x * TM;
    const int b   = blockIdx.y;
    const size_t xbase = (size_t)b * NN * DDIM;

    // ---- Phase 1: gather -> z bf16 (64 nodes x 4 nbrs x 10 float4 = 2560 tasks);
    //      k==0 (self row) additionally stashed f32 in xself for the epilogue ----
    for (int e = tid; e < TM * 4 * 10; e += NTHR) {
        int m = e / 40, r = e - m * 40;
        int k = r / 10, qq = r - k * 10;
        unsigned int lo = 0, hi = 0;
        int n = n0 + m;
        if (n < NN) {
            int nb = index[n * 4 + k];
            float4 v = ((const float4*)(xsrc + xbase + (size_t)nb * DDIM))[qq];
            lo = cvt_pk_bf16(v.x, v.y);
            hi = cvt_pk_bf16(v.z, v.w);
            if (k == 0) *(float4*)(xself + m * 40 + qq * 4) = v;
        }
        *(uint2*)(z + m * ZS + k * 40 + qq * 4) = make_uint2(lo, hi);
    }
    __syncthreads();

    // ---- Phase 2: GEMM1  h^T = W1^T(A) . z^T(B) ; wave owns hid tiles w*2, w*2+1; 4 node tiles ----
    f32x4 acc[2][4];
    #pragma unroll
    for (int i = 0; i < 2; ++i) {
        float4 bv = *(const float4*)(b1 + (w * 2 + i) * 16 + q * 4);
        f32x4 a; a[0] = bv.x; a[1] = bv.y; a[2] = bv.z; a[3] = bv.w;
        #pragma unroll
        for (int nt = 0; nt < 4; ++nt) acc[i][nt] = a;
    }
    #pragma unroll
    for (int kk = 0; kk < 5; ++kk) {
        short8 afr0 = *(const short8*)(W1p + (size_t)(((w * 2 + 0) * 5 + kk) * 512 + ln * 8));
        short8 afr1 = *(const short8*)(W1p + (size_t)(((w * 2 + 1) * 5 + kk) * 512 + ln * 8));
        #pragma unroll
        for (int nt = 0; nt < 4; ++nt) {
            short8 bfr = *(const short8*)(z + (nt * 16 + nl) * ZS + kk * 32 + q * 8);
            acc[0][nt] = __builtin_amdgcn_mfma_f32_16x16x32_bf16(afr0, bfr, acc[0][nt], 0, 0, 0);
            acc[1][nt] = __builtin_amdgcn_mfma_f32_16x16x32_bf16(afr1, bfr, acc[1][nt], 0, 0, 0);
        }
    }
    __syncthreads();   // all z reads done (fz overlays z later)

    // ---- Phase 3: h = fp8(gelu(acc)) : one b32 write per (i,nt) ----
    #pragma unroll
    for (int i = 0; i < 2; ++i) {
        const int hid  = (w * 2 + i) * 16 + q * 4;
        const int sub8 = hid >> 3;          // = (w*2+i)*2 + (q>>1)
        const int o4   = (q & 1) << 2;
        #pragma unroll
        for (int nt = 0; nt < 4; ++nt) {
            f32x4 a = acc[i][nt];
            unsigned int p = pk4_fp8(gelu_fast(a[0]), gelu_fast(a[1]),
                                     gelu_fast(a[2]), gelu_fast(a[3]));
            int node = nt * 16 + nl;
            *(unsigned int*)(h + node * 512 + ((sub8 ^ (node & 7)) << 3) + o4) = p;
        }
    }
    __syncthreads();

    // ---- Phase 4: GEMM2 fz^T = W2^T(A) . h^T(B), fp8; 16 waves = 2 Khalf x 2 jt x 4 node tiles ----
    const int nt2 = w & 3;           // node tile
    const int jt  = (w >> 2) & 1;    // output j tile
    const int kh  = (w >> 3) & 1;    // K half
    const int hrow = nt2 * 16 + nl;
    f32x4 acc2;
    if (kh == 0) {
        float4 bv = *(const float4*)(b2 + jt * 16 + q * 4);
        acc2[0] = bv.x; acc2[1] = bv.y; acc2[2] = bv.z; acc2[3] = bv.w;
    } else {
        acc2[0] = acc2[1] = acc2[2] = acc2[3] = 0.f;
    }
    #pragma unroll
    for (int kk = 0; kk < 8; ++kk) {
        int kg = kh * 8 + kk;
        long long afr, bfr;
        __builtin_memcpy(&afr, W2p + (size_t)(((jt * 16 + kg) * 64 + ln) * 8), 8);
        __builtin_memcpy(&bfr, h + hrow * 512 + (((kg * 4 + q) ^ (hrow & 7)) << 3), 8);
        acc2 = __builtin_amdgcn_mfma_f32_16x16x32_fp8_fp8(afr, bfr, acc2, 0, 0, 0);
    }
    {   // partial -> fz[kh] (overlay z; z is dead)
        float* fzk = kh ? fz1 : fz0;
        *(f32x4*)(fzk + hrow * 36 + jt * 16 + q * 4) = acc2;
    }
    __syncthreads();

    // ---- Phase 5: epilogue, 64 rows x 10 float4 = 640 tasks; x base row from LDS (no global read) ----
    if (tid < TM * 10) {
        int m = tid / 10, p = tid - m * 10;
        int n = n0 + m;
        if (n < NN) {
            float4 v = *(const float4*)(xself + m * 40 + p * 4);
            if (p < 8) {
                f32x4 f0 = *(const f32x4*)(fz0 + m * 36 + p * 4);
                f32x4 f1 = *(const f32x4*)(fz1 + m * 36 + p * 4);
                v.x = fmaf(STEPSZ, f0[0] + f1[0], v.x);
                v.y = fmaf(STEPSZ, f0[1] + f1[1], v.y);
                v.z = fmaf(STEPSZ, f0[2] + f1[2], v.z);
                v.w = fmaf(STEPSZ, f0[3] + f1[3], v.w);
            }
            *(float4*)(xdst + xbase + (size_t)n * DDIM + p * 4) = v;
        }
    }
}

// ================= fallback f32 path (used only if ws too small) =================
constexpr int FTM = 16;
__device__ __forceinline__ float gelu_f(float x) { return gelu_fast(x); }
__global__ __launch_bounds__(256) void step_f32(
    const float* __restrict__ xsrc, float* __restrict__ xdst,
    const int* __restrict__ index,
    const float* __restrict__ W1, const float* __restrict__ b1,
    const float* __restrict__ W2, const float* __restrict__ b2)
{
    __shared__ float z_lds[FTM][160];
    __shared__ float h_lds[FTM][HH];
    __shared__ float fz_lds[FTM][DDYN];
    const int tid = threadIdx.x, tile = blockIdx.x, b = blockIdx.y;
    const int n0 = tile * FTM;
    const int nvalid = min(FTM, NN - n0);
    for (int e = tid; e < FTM * 4 * 10; e += 256) {
        int m = e / 40, r = e % 40, k = r / 10, qq = r % 10;
        float4 v = make_float4(0.f, 0.f, 0.f, 0.f);
        int n = n0 + m;
        if (n < NN) {
            int nb = index[n * 4 + k];
            v = ((const float4*)(xsrc + ((size_t)b * NN + nb) * DDIM))[qq];
        }
        ((float4*)&z_lds[m][k * DDIM])[qq] = v;
    }
    __syncthreads();
    const int c0 = 2 * tid;
    float2 acc[FTM];
    {
        float bx = b1[c0], by = b1[c0 + 1];
        #pragma unroll
        for (int m = 0; m < FTM; ++m) { acc[m].x = bx; acc[m].y = by; }
    }
    for (int kd = 0; kd < 160; kd += 4) {
        float2 w0 = *(const float2*)(W1 + (size_t)(kd + 0) * HH + c0);
        float2 w1 = *(const float2*)(W1 + (size_t)(kd + 1) * HH + c0);
        float2 w2 = *(const float2*)(W1 + (size_t)(kd + 2) * HH + c0);
        float2 w3 = *(const float2*)(W1 + (size_t)(kd + 3) * HH + c0);
        #pragma unroll
        for (int m = 0; m < FTM; ++m) {
            float4 zv = *(const float4*)&z_lds[m][kd];
            acc[m].x = fmaf(zv.x, w0.x, acc[m].x); acc[m].y = fmaf(zv.x, w0.y, acc[m].y);
            acc[m].x = fmaf(zv.y, w1.x, acc[m].x); acc[m].y = fmaf(zv.y, w1.y, acc[m].y);
            acc[m].x = fmaf(zv.z, w2.x, acc[m].x); acc[m].y = fmaf(zv.z, w2.y, acc[m].y);
            acc[m].x = fmaf(zv.w, w3.x, acc[m].x); acc[m].y = fmaf(zv.w, w3.y, acc[m].y);
        }
    }
    #pragma unroll
    for (int m = 0; m < FTM; ++m) {
        h_lds[m][c0]     = gelu_f(acc[m].x);
        h_lds[m][c0 + 1] = gelu_f(acc[m].y);
    }
    __syncthreads();
    {
        const int j = tid & 31, mg = tid >> 5;
        float a0 = b2[j], a1 = a0;
        for (int c = 0; c < HH; c += 4) {
            float wa = W2[(size_t)(c + 0) * DDYN + j];
            float wb = W2[(size_t)(c + 1) * DDYN + j];
            float wc = W2[(size_t)(c + 2) * DDYN + j];
            float wd = W2[(size_t)(c + 3) * DDYN + j];
            float4 h0 = *(const float4*)&h_lds[mg][c];
            float4 h1 = *(const float4*)&h_lds[mg + 8][c];
            a0 = fmaf(h0.x, wa, a0); a0 = fmaf(h0.y, wb, a0);
            a0 = fmaf(h0.z, wc, a0); a0 = fmaf(h0.w, wd, a0);
            a1 = fmaf(h1.x, wa, a1); a1 = fmaf(h1.y, wb, a1);
            a1 = fmaf(h1.z, wc, a1); a1 = fmaf(h1.w, wd, a1);
        }
        fz_lds[mg][j] = a0; fz_lds[mg + 8][j] = a1;
    }
    __syncthreads();
    const size_t base = ((size_t)b * NN + n0) * (size_t)DDIM;
    for (int e = tid; e < nvalid * DDIM; e += 256) {
        int m = e / DDIM, d = e % DDIM;
        float v = xsrc[base + e];
        if (d < DDYN) v = fmaf(STEPSZ, fz_lds[m][d], v);
        xdst[base + e] = v;
    }
}

extern "C" void kernel_launch(void* const* d_in, const int* in_sizes, int n_in,
                              void* d_out, int out_size, void* d_ws, size_t ws_size,
                              hipStream_t stream) {
    const float* x   = (const float*)d_in[0];
    const int*   idx = (const int*)  d_in[1];
    const float* W1  = (const float*)d_in[2];
    const float* b1  = (const float*)d_in[3];
    const float* W2  = (const float*)d_in[4];
    const float* b2  = (const float*)d_in[5];
    float* out  = (float*)d_out;
    float* xbuf = (float*)d_ws;

    const size_t need = X_BYTES + (size_t)W1P_ELEMS * 2 + W2P_BYTES;
    if (ws_size >= need) {
        unsigned short* W1p = (unsigned short*)((char*)d_ws + X_BYTES);
        unsigned char*  W2p = (unsigned char*)(W1p + W1P_ELEMS);
        pack_w1<<<(W1P_ELEMS + 255) / 256, 256, 0, stream>>>(W1, W1p);
        pack_w2_fp8<<<(W2P_BYTES + 255) / 256, 256, 0, stream>>>(W2, W2p);
        dim3 grid((NN + TM - 1) / TM, BB), block(NTHR);
        step_mfma<<<grid, block, 0, stream>>>(x,    xbuf, idx, W1p, b1, W2p, b2);
        step_mfma<<<grid, block, 0, stream>>>(xbuf, out,  idx, W1p, b1, W2p, b2);
        step_mfma<<<grid, block, 0, stream>>>(out,  xbuf, idx, W1p, b1, W2p, b2);
        step_mfma<<<grid, block, 0, stream>>>(xbuf, out,  idx, W1p, b1, W2p, b2);
    } else {
        dim3 grid((NN + FTM - 1) / FTM, BB), block(256);
        step_f32<<<grid, block, 0, stream>>>(x,    xbuf, idx, W1, b1, W2, b2);
        step_f32<<<grid, block, 0, stream>>>(xbuf, out,  idx, W1, b1, W2, b2);
        step_f32<<<grid, block, 0, stream>>>(out,  xbuf, idx, W1, b1, W2, b2);
        step_f32<<<grid, block, 0, stream>>>(xbuf, out,  idx, W1, b1, W2, b2);
    }
}